// Round 6
// baseline (356.674 us; speedup 1.0000x reference)
//
#include <hip/hip_runtime.h>
#include <hip/hip_bf16.h>

// Problem constants (from reference)
#define N_NODES 50000
#define N_EDGES 150000
#define NODE_IN 64
#define EDGE_IN 16
#define DD 32          // node feature dim
#define EHID 128       // edge-network hidden
#define STEPS 3
#define EPB 128        // edges per fused_msg block: LDS 39424B -> 4 blocks/CU
#define NSCAN 196      // ceil(N_NODES/256) scan blocks

// Device-verified harness dtypes: float inputs fp32, edge_index int32, output fp32.
__device__ __forceinline__ ushort f2b(float f) {
    __hip_bfloat16 b = __float2bfloat16(f);   // RNE
    return *reinterpret_cast<ushort*>(&b);
}
__device__ __forceinline__ float b2f(ushort u) {
    unsigned int x = ((unsigned int)u) << 16;
    return __uint_as_float(x);
}

typedef __bf16 bf16x8 __attribute__((ext_vector_type(8)));
typedef float  f32x4  __attribute__((ext_vector_type(4)));

#define LDA  136   // As leading dim (ushorts)
#define HPAD 36    // Hs leading dim (floats)
#define MPAD 40    // Ms leading dim (ushorts), 80B rows -> 16B-aligned

// ---------------------------------------------------------------------------
// prep: repack weights into MFMA-fragment-major bf16 buffers. (unchanged)
__global__ __launch_bounds__(256) void prep(const float* __restrict__ we2,
                                            const float* __restrict__ we1,
                                            const float* __restrict__ wroot,
                                            const float* __restrict__ wih,
                                            const float* __restrict__ whh,
                                            ushort* __restrict__ we2B,
                                            ushort* __restrict__ we1B,
                                            ushort* __restrict__ wgB) {
    int i = blockIdx.x * 256 + threadIdx.x;
    if (i < 16384) {
        int l = i & 63, f = i >> 6;           // f = bn*16 + nt*4 + kt
        int kt = f & 3, nt = (f >> 2) & 3, bn = f >> 4;
        int lr = l & 15, lg = l >> 4;
        int n = bn * 64 + nt * 16 + lr;
        int k0 = kt * 32 + lg * 8;
        ushort tmp[8];
#pragma unroll
        for (int j = 0; j < 8; ++j) tmp[j] = f2b(we2[(size_t)(k0 + j) * 1024 + n]);
        *(uint4*)(we2B + (size_t)i * 8) = *(uint4*)tmp;
    } else if (i < 16896) {
        int u = i - 16384;
        int l = u & 63, nt = u >> 6;
        int lr = l & 15, lg = l >> 4;
        int n = nt * 16 + lr;
        ushort tmp[8];
#pragma unroll
        for (int j = 0; j < 8; ++j) {
            int k = lg * 8 + j;
            tmp[j] = (k < EDGE_IN) ? f2b(we1[(size_t)k * EHID + n]) : (ushort)0;
        }
        *(uint4*)(we1B + (size_t)u * 8) = *(uint4*)tmp;
    } else if (i < 17792) {
        int u = i - 16896;
        int l = u & 63;
        int lr = l & 15, lg = l >> 4;
        ushort tmp[8];
        if (u < 128) {            // Wroot [i][o] row-major
            int nt = u >> 6;
#pragma unroll
            for (int j = 0; j < 8; ++j)
                tmp[j] = f2b(wroot[(size_t)(lg * 8 + j) * DD + nt * 16 + lr]);
        } else if (u < 512) {     // Wih [3D][D] row-major, B[n=gate-row][k=i]
            int nt = (u - 128) >> 6;
#pragma unroll
            for (int j = 0; j < 8; ++j)
                tmp[j] = f2b(wih[(size_t)(nt * 16 + lr) * DD + lg * 8 + j]);
        } else {                  // Whh
            int nt = (u - 512) >> 6;
#pragma unroll
            for (int j = 0; j < 8; ++j)
                tmp[j] = f2b(whh[(size_t)(nt * 16 + lr) * DD + lg * 8 + j]);
        }
        *(uint4*)(wgB + (size_t)u * 8) = *(uint4*)tmp;
    }
}

// ---------------------------------------------------------------------------
// CSR build (one-time): indegree hist -> multi-block exclusive scan -> fill.
__global__ __launch_bounds__(256) void hist(const int* __restrict__ ei,
                                            int* __restrict__ cnt) {
    int e = blockIdx.x * 256 + threadIdx.x;
    if (e < N_EDGES) atomicAdd(&cnt[ei[N_EDGES + e]], 1);
}

// Per-block exclusive scan of cnt (in place), block totals -> bsum.
__global__ __launch_bounds__(256) void scan1(int* __restrict__ cnt,
                                             int* __restrict__ bsum) {
    __shared__ int wsum[4];
    int b = blockIdx.x, t = threadIdx.x;
    int lane = t & 63, wid = t >> 6;
    int i = b * 256 + t;
    int v = (i < N_NODES) ? cnt[i] : 0;
    int s = v;
#pragma unroll
    for (int off = 1; off < 64; off <<= 1) {
        int u = __shfl_up(s, off);
        if (lane >= off) s += u;
    }
    if (lane == 63) wsum[wid] = s;
    __syncthreads();
    if (t == 0) {
        int a = 0;
#pragma unroll
        for (int k = 0; k < 4; ++k) { int tmp = wsum[k]; wsum[k] = a; a += tmp; }
    }
    __syncthreads();
    int excl = s - v + wsum[wid];
    if (i < N_NODES) cnt[i] = excl;
    if (t == 255) bsum[b] = excl + v;
}

// Exclusive scan of the NSCAN block sums (single block, NSCAN <= 256).
__global__ __launch_bounds__(256) void scan2(int* __restrict__ bsum) {
    __shared__ int wsum[4];
    int t = threadIdx.x;
    int lane = t & 63, wid = t >> 6;
    int v = (t < NSCAN) ? bsum[t] : 0;
    int s = v;
#pragma unroll
    for (int off = 1; off < 64; off <<= 1) {
        int u = __shfl_up(s, off);
        if (lane >= off) s += u;
    }
    if (lane == 63) wsum[wid] = s;
    __syncthreads();
    if (t == 0) {
        int a = 0;
#pragma unroll
        for (int k = 0; k < 4; ++k) { int tmp = wsum[k]; wsum[k] = a; a += tmp; }
    }
    __syncthreads();
    if (t < NSCAN) bsum[t] = s - v + wsum[wid];
}

// off = cur = local-scan + block offset.
__global__ __launch_bounds__(256) void scan3(const int* __restrict__ cnt,
                                             const int* __restrict__ bsum,
                                             int* __restrict__ off,
                                             int* __restrict__ cur) {
    int i = blockIdx.x * 256 + threadIdx.x;
    if (i < N_NODES) {
        int o = cnt[i] + bsum[blockIdx.x];
        off[i] = o;
        cur[i] = o;
    }
}

__global__ __launch_bounds__(256) void scatter_fill(const int* __restrict__ ei,
                                                    int* __restrict__ cur,
                                                    int* __restrict__ perm) {
    int e = blockIdx.x * 256 + threadIdx.x;
    if (e >= N_EDGES) return;
    int d = ei[N_EDGES + e];
    int pos = atomicAdd(&cur[d], 1);
    perm[pos] = e;
}

// ---------------------------------------------------------------------------
// node_init (round-10 proven form): thread = node, uniform LDS weight reads.
__global__ __launch_bounds__(256) void node_init(const float* __restrict__ x,
                                                 const float* __restrict__ Wn,
                                                 const float* __restrict__ bn,
                                                 float* __restrict__ h) {
    __shared__ float Wns[NODE_IN * DD];   // 8 KB
    __shared__ float bns[DD];
    int t = threadIdx.x;
    for (int i = t; i < NODE_IN * DD; i += 256) Wns[i] = Wn[i];
    if (t < DD) bns[t] = bn[t];
    __syncthreads();
    int n = blockIdx.x * 256 + t;
    if (n >= N_NODES) return;
    float xr[NODE_IN];
    const float4* xp = (const float4*)(x + (size_t)n * NODE_IN);
#pragma unroll
    for (int q = 0; q < NODE_IN / 4; ++q) *(float4*)&xr[q * 4] = xp[q];
    float out[DD];
#pragma unroll
    for (int o = 0; o < DD; ++o) {
        float s = bns[o];
#pragma unroll
        for (int i = 0; i < NODE_IN; ++i) s += xr[i] * Wns[i * DD + o];
        out[o] = fmaxf(s, 0.f);
    }
    float4* hp = (float4*)(h + (size_t)n * DD);
#pragma unroll
    for (int q = 0; q < DD / 4; ++q) hp[q] = *(float4*)&out[q * 4];
}

// ---------------------------------------------------------------------------
// fused_msg R6: R5 body with the tail copy-width BUG FIXED (R5 copied only
// 16B of each 64B msg row per thread pair -> half the columns were garbage;
// absmax 1.17e-1). Each thread now copies its 2 uint4s (32B). Zero atomics.
__global__ __launch_bounds__(256, 4) void fused_msg(const float* __restrict__ ea,
                                                    const ushort* __restrict__ we1B,
                                                    const float* __restrict__ be1,
                                                    const ushort* __restrict__ we2B,
                                                    const float* __restrict__ be2,
                                                    const int* __restrict__ ei,
                                                    const float* __restrict__ h,
                                                    ushort* __restrict__ msg) {
    __shared__ __attribute__((aligned(16))) ushort AsHs[EPB * LDA];  // 34816 B
    __shared__ float b1s[EHID];                                      // 512 B
    __shared__ float be2s[DD * DD];                                  // 4096 B
    float* Hs = (float*)AsHs;            // [128][HPAD] fp32 view (phase B)
    ushort* Bs = AsHs + 9216;            // bytes [18432, 34816): bn weight tile
    ushort* Ms = AsHs;                   // [128][MPAD] bf16 m staging (tail)

    int t = threadIdx.x;
    if (t < EHID) b1s[t] = be1[t];
    for (int i = t; i < DD * DD; i += 256) be2s[i] = be2[i];

    int w = t >> 6, l = t & 63;
    int lr = l & 15, lg = l >> 4;
    int e0 = blockIdx.x * EPB;

    // Phase A input fragments straight from global (direct, coalesced)
    bf16x8 afe[2];
#pragma unroll
    for (int mi = 0; mi < 2; ++mi) {
        int e = e0 + (w * 2 + mi) * 16 + lr;
        ushort tmp[8] = {0, 0, 0, 0, 0, 0, 0, 0};
        if (lg < 2 && e < N_EDGES) {
            const float4* p = (const float4*)(ea + (size_t)e * EDGE_IN + lg * 8);
            float4 a = p[0], b = p[1];
            tmp[0] = f2b(a.x); tmp[1] = f2b(a.y); tmp[2] = f2b(a.z); tmp[3] = f2b(a.w);
            tmp[4] = f2b(b.x); tmp[5] = f2b(b.y); tmp[6] = f2b(b.z); tmp[7] = f2b(b.w);
        }
        afe[mi] = *(bf16x8*)tmp;
    }
    __syncthreads();   // (1) b1s ready

    // Phase A: g = relu(ea@We1+be1) via MFMA -> bf16 As[128][128]
#pragma unroll
    for (int nt = 0; nt < 8; ++nt) {
        bf16x8 bfe = *(const bf16x8*)(we1B + (size_t)((nt << 6) + l) * 8);
        int kh = nt * 16 + lr;
        float bb = b1s[kh];
#pragma unroll
        for (int mi = 0; mi < 2; ++mi) {
            f32x4 acc = (f32x4){0.f, 0.f, 0.f, 0.f};
            acc = __builtin_amdgcn_mfma_f32_16x16x32_bf16(afe[mi], bfe, acc, 0, 0, 0);
#pragma unroll
            for (int r = 0; r < 4; ++r)
                AsHs[((w * 2 + mi) * 16 + lg * 4 + r) * LDA + kh] = f2b(fmaxf(acc[r] + bb, 0.f));
        }
    }
    __syncthreads();   // (2) As complete

    bf16x8 afrag[2][4];
#pragma unroll
    for (int mi = 0; mi < 2; ++mi)
#pragma unroll
        for (int kt = 0; kt < 4; ++kt)
            afrag[mi][kt] = *(const bf16x8*)(&AsHs[((w * 2 + mi) * 16 + lr) * LDA + kt * 32 + lg * 8]);
    __syncthreads();   // (3) As reads done -> region becomes Hs + Bs

    // Gather h[src] into Hs (2 threads per edge row)
    {
        int row = t >> 1, half = t & 1;
        int e = e0 + row;
        float4* hd = (float4*)(Hs + row * HPAD) + half * 4;
        if (e < N_EDGES) {
            const float4* hr = (const float4*)(h + (size_t)ei[e] * DD) + half * 4;
#pragma unroll
            for (int q = 0; q < 4; ++q) hd[q] = hr[q];
        } else {
            float4 z = make_float4(0.f, 0.f, 0.f, 0.f);
#pragma unroll
            for (int q = 0; q < 4; ++q) hd[q] = z;
        }
    }
    // Stage bn=0 weight tile: L2 -> LDS DMA, no VGPR round-trip.
#pragma unroll
    for (int q = 0; q < 4; ++q) {
        const ushort* gsrc = we2B + (size_t)(q * 256 + t) * 8;          // per-lane
        ushort* ldst = Bs + (size_t)(q * 256 + w * 64) * 8;             // wave-uniform
        __builtin_amdgcn_global_load_lds(
            (const __attribute__((address_space(1))) unsigned int*)gsrc,
            (__attribute__((address_space(3))) unsigned int*)ldst, 16, 0, 0);
    }
    asm volatile("s_waitcnt vmcnt(0)" ::: "memory");
    __syncthreads();   // (4) Hs + Bs(0) ready

    float m_acc[2][4][2];
#pragma unroll
    for (int mi = 0; mi < 2; ++mi)
#pragma unroll
        for (int r = 0; r < 4; ++r) { m_acc[mi][r][0] = 0.f; m_acc[mi][r][1] = 0.f; }

    for (int bn = 0; bn < 16; ++bn) {
        float bv[4];
#pragma unroll
        for (int nt = 0; nt < 4; ++nt) bv[nt] = be2s[bn * 64 + nt * 16 + lr];

        f32x4 acc[2][4];
#pragma unroll
        for (int mi = 0; mi < 2; ++mi)
#pragma unroll
            for (int nt = 0; nt < 4; ++nt) acc[mi][nt] = (f32x4){0.f, 0.f, 0.f, 0.f};

#pragma unroll
        for (int kt = 0; kt < 4; ++kt) {
            const ushort* base = Bs + (size_t)(kt * 64 + l) * 8;
            bf16x8 b0 = *(const bf16x8*)(base);
            bf16x8 b1 = *(const bf16x8*)(base + 2048);
            bf16x8 b2 = *(const bf16x8*)(base + 4096);
            bf16x8 b3 = *(const bf16x8*)(base + 6144);
#pragma unroll
            for (int mi = 0; mi < 2; ++mi) {
                acc[mi][0] = __builtin_amdgcn_mfma_f32_16x16x32_bf16(afrag[mi][kt], b0, acc[mi][0], 0, 0, 0);
                acc[mi][1] = __builtin_amdgcn_mfma_f32_16x16x32_bf16(afrag[mi][kt], b1, acc[mi][1], 0, 0, 0);
                acc[mi][2] = __builtin_amdgcn_mfma_f32_16x16x32_bf16(afrag[mi][kt], b2, acc[mi][2], 0, 0, 0);
                acc[mi][3] = __builtin_amdgcn_mfma_f32_16x16x32_bf16(afrag[mi][kt], b3, acc[mi][3], 0, 0, 0);
            }
        }

        // Fold: col=bn*64+nt*16+lr -> i=2bn+(nt>>1), o=16*(nt&1)+lr
#pragma unroll
        for (int mi = 0; mi < 2; ++mi) {
#pragma unroll
            for (int r = 0; r < 4; ++r) {
                int row = (w * 2 + mi) * 16 + lg * 4 + r;
                float2 hv = *(const float2*)(Hs + row * HPAD + bn * 2);
#pragma unroll
                for (int nt = 0; nt < 4; ++nt) {
                    float hi = (nt >> 1) ? hv.y : hv.x;
                    m_acc[mi][r][nt & 1] += hi * (acc[mi][nt][r] + bv[nt]);
                }
            }
        }

        if (bn < 15) {
            __syncthreads();   // all waves done reading Bs(bn)
#pragma unroll
            for (int q = 0; q < 4; ++q) {
                const ushort* gsrc = we2B + (size_t)(bn + 1) * 8192 + (size_t)(q * 256 + t) * 8;
                ushort* ldst = Bs + (size_t)(q * 256 + w * 64) * 8;
                __builtin_amdgcn_global_load_lds(
                    (const __attribute__((address_space(1))) unsigned int*)gsrc,
                    (__attribute__((address_space(3))) unsigned int*)ldst, 16, 0, 0);
            }
            asm volatile("s_waitcnt vmcnt(0)" ::: "memory");
            __syncthreads();   // Bs(bn+1) ready
        }
    }

    // Tail: m -> LDS (bf16) -> coalesced global stores. Zero atomics.
    __syncthreads();   // all folds done reading Hs before Ms overwrites it
#pragma unroll
    for (int mi = 0; mi < 2; ++mi) {
#pragma unroll
        for (int r = 0; r < 4; ++r) {
            int row = (w * 2 + mi) * 16 + lg * 4 + r;
            Ms[row * MPAD + lr]      = f2b(m_acc[mi][r][0]);
            Ms[row * MPAD + lr + 16] = f2b(m_acc[mi][r][1]);
        }
    }
    __syncthreads();
    {
        int row = t >> 1, half = t & 1;
        int e = e0 + row;
        if (e < N_EDGES) {
            // FIX (R5 bug): copy BOTH uint4s of this thread's 32B half.
            const uint4* src = (const uint4*)(Ms + row * MPAD);
            uint4* dst = (uint4*)(msg + (size_t)e * DD);
            dst[half * 2]     = src[half * 2];
            dst[half * 2 + 1] = src[half * 2 + 1];
        }
    }
}

// ---------------------------------------------------------------------------
// conv_gru R6: agg read replaced by CSR gather-sum over bf16 msg rows.
// h updated IN PLACE (h aliases d_out; final h is the output). Block owns
// its 64 nodes exclusively -> in-place safe.
__global__ __launch_bounds__(256) void conv_gru(const ushort* __restrict__ msg,
                                                const int* __restrict__ perm,
                                                const int* __restrict__ off,
                                                float* __restrict__ h,
                                                const ushort* __restrict__ wgB,
                                                const float* __restrict__ bconv,
                                                const float* __restrict__ bih,
                                                const float* __restrict__ bhh) {
    __shared__ __attribute__((aligned(16))) ushort Ah[64 * 40];   // 5120 B
    __shared__ __attribute__((aligned(16))) ushort Ac[64 * 40];   // 5120 B
    __shared__ float hs[64 * 33];                                 // 8448 B
    __shared__ float bcs[DD], bis[3 * DD], bhs[3 * DD];
    int t = threadIdx.x;
    int base = blockIdx.x * 64;

    for (int idx = t; idx < 64 * DD; idx += 256) {
        int row = idx >> 5, col = idx & 31;
        int n = base + row;
        float v = (n < N_NODES) ? h[(size_t)n * DD + col] : 0.f;
        hs[row * 33 + col] = v;
        Ah[row * 40 + col] = f2b(v);
    }
    if (t < DD) bcs[t] = bconv[t];
    if (t < 3 * DD) { bis[t] = bih[t]; bhs[t] = bhh[t]; }
    __syncthreads();

    int w = t >> 6, l = t & 63;
    int lr = l & 15, lg = l >> 4;
    const f32x4 zro = (f32x4){0.f, 0.f, 0.f, 0.f};

    bf16x8 ah = *(const bf16x8*)(&Ah[(w * 16 + lr) * 40 + lg * 8]);

    // conv GEMM (2 n-tiles, K=32)
    f32x4 dcv[2];
#pragma unroll
    for (int nt = 0; nt < 2; ++nt) {
        bf16x8 b = *(const bf16x8*)(wgB + (size_t)(nt * 64 + l) * 8);
        dcv[nt] = __builtin_amdgcn_mfma_f32_16x16x32_bf16(ah, b, zro, 0, 0, 0);
    }
    // epilogue: conv = relu(dcv + gather(msg) + bc) -> bf16 Ac
#pragma unroll
    for (int r = 0; r < 4; ++r) {
        int row = w * 16 + lg * 4 + r;
        int n = base + row;
        float a0 = 0.f, a1 = 0.f;
        if (n < N_NODES) {
            int beg = off[n];
            int end = (n + 1 < N_NODES) ? off[n + 1] : N_EDGES;
            for (int j = beg; j < end; ++j) {
                int e = perm[j];
                const ushort* mr = msg + (size_t)e * DD;
                a0 += b2f(mr[lr]);
                a1 += b2f(mr[lr + 16]);
            }
        }
        Ac[row * 40 + lr]      = f2b(fmaxf(dcv[0][r] + a0 + bcs[lr], 0.f));
        Ac[row * 40 + lr + 16] = f2b(fmaxf(dcv[1][r] + a1 + bcs[lr + 16], 0.f));
    }
    __syncthreads();

    bf16x8 ac = *(const bf16x8*)(&Ac[(w * 16 + lr) * 40 + lg * 8]);

    // gate GEMMs: gi = conv@Wih^T (+bi), gh = h@Whh^T (+bh); 6 n-tiles each
    f32x4 gi[6], gh[6];
#pragma unroll
    for (int nt = 0; nt < 6; ++nt) {
        bf16x8 bi_ = *(const bf16x8*)(wgB + (size_t)(128 + nt * 64 + l) * 8);
        gi[nt] = __builtin_amdgcn_mfma_f32_16x16x32_bf16(ac, bi_, zro, 0, 0, 0);
        bf16x8 bh_ = *(const bf16x8*)(wgB + (size_t)(512 + nt * 64 + l) * 8);
        gh[nt] = __builtin_amdgcn_mfma_f32_16x16x32_bf16(ah, bh_, zro, 0, 0, 0);
    }

    // elementwise GRU in D-layout: col = gate*32 + ch*16 + lr -> tile gate*2+ch
#pragma unroll
    for (int r = 0; r < 4; ++r) {
        int row = w * 16 + lg * 4 + r;
        int n = base + row;
        if (n >= N_NODES) continue;
#pragma unroll
        for (int ch = 0; ch < 2; ++ch) {
            int o = ch * 16 + lr;
            float girv = gi[ch][r]     + bis[o];
            float gizv = gi[2 + ch][r] + bis[DD + o];
            float ginv = gi[4 + ch][r] + bis[2 * DD + o];
            float ghrv = gh[ch][r]     + bhs[o];
            float ghzv = gh[2 + ch][r] + bhs[DD + o];
            float ghnv = gh[4 + ch][r] + bhs[2 * DD + o];
            float R  = 1.f / (1.f + expf(-(girv + ghrv)));
            float Z  = 1.f / (1.f + expf(-(gizv + ghzv)));
            float Nn = tanhf(ginv + R * ghnv);
            float hold = hs[row * 33 + o];
            float hnew = (1.f - Z) * Nn + Z * hold;
            h[(size_t)n * DD + o] = hnew;   // in place; h aliases d_out
        }
    }
}

// ---------------------------------------------------------------------------
extern "C" void kernel_launch(void* const* d_in, const int* in_sizes, int n_in,
                              void* d_out, int out_size, void* d_ws, size_t ws_size,
                              hipStream_t stream) {
    const float* x    = (const float*)d_in[0];
    const int*   ei   = (const int*)d_in[1];
    const float* ea   = (const float*)d_in[2];
    const float* Wn   = (const float*)d_in[3];
    const float* bn   = (const float*)d_in[4];
    const float* We1  = (const float*)d_in[5];
    const float* be1  = (const float*)d_in[6];
    const float* We2  = (const float*)d_in[7];
    const float* be2  = (const float*)d_in[8];
    const float* Wroot= (const float*)d_in[9];
    const float* bconv= (const float*)d_in[10];
    const float* Wih  = (const float*)d_in[11];
    const float* Whh  = (const float*)d_in[12];
    const float* bih  = (const float*)d_in[13];
    const float* bhh  = (const float*)d_in[14];

    // ---- Workspace: 11.09 MB (< proven 13.34 MB). h aliases d_out:
    //      conv_gru updates h in place, final h IS the output.
    char* ws = (char*)d_ws;
    ushort* msg  = (ushort*)(ws);                   // 9,600,000 E x 32 bf16 messages
    ushort* we2B = (ushort*)(ws + 9600000);         //   262,144 fragment-major We2T
    ushort* we1B = (ushort*)(ws + 9862144);         //     8,192 fragment-major We1T
    ushort* wgB  = (ushort*)(ws + 9870336);         //    14,336 fragment-major GRU weights
    int*    cnt  = (int*)(ws + 9884672);            //   200,000 hist / local scan
    int*    off  = (int*)(ws + 10084672);           //   200,000 CSR offsets
    int*    cur  = (int*)(ws + 10284672);           //   200,000 fill cursors
    int*    perm = (int*)(ws + 10484672);           //   600,000 CSR edge ids
    int*    bsum = (int*)(ws + 11084672);           //     1,024 scan block sums
    float*  h    = (float*)d_out;                   // 6.4 MB node state (= output)

    // One-time CSR build (multi-block scan, ~10us total)
    hipMemsetAsync(cnt, 0, (size_t)N_NODES * sizeof(int), stream);
    prep<<<70, 256, 0, stream>>>(We2, We1, Wroot, Wih, Whh, we2B, we1B, wgB);
    node_init<<<(N_NODES + 255) / 256, 256, 0, stream>>>(x, Wn, bn, h);
    hist<<<(N_EDGES + 255) / 256, 256, 0, stream>>>(ei, cnt);
    scan1<<<NSCAN, 256, 0, stream>>>(cnt, bsum);
    scan2<<<1, 256, 0, stream>>>(bsum);
    scan3<<<NSCAN, 256, 0, stream>>>(cnt, bsum, off, cur);
    scatter_fill<<<(N_EDGES + 255) / 256, 256, 0, stream>>>(ei, cur, perm);

    for (int step = 0; step < STEPS; ++step) {
        fused_msg<<<(N_EDGES + EPB - 1) / EPB, 256, 0, stream>>>(ea, we1B, be1, we2B, be2,
                                                                 ei, h, msg);
        conv_gru<<<(N_NODES + 63) / 64, 256, 0, stream>>>(msg, perm, off, h, wgB,
                                                          bconv, bih, bhh);
    }
}

// Round 7
// 354.188 us; speedup vs baseline: 1.0070x; 1.0070x over previous
//
#include <hip/hip_runtime.h>
#include <hip/hip_bf16.h>

// Problem constants (from reference)
#define N_NODES 50000
#define N_EDGES 150000
#define NODE_IN 64
#define EDGE_IN 16
#define DD 32          // node feature dim
#define EHID 128       // edge-network hidden
#define STEPS 3
#define EPB 128        // edges per fused_msg block: LDS 39424B -> 4 blocks/CU
#define NSCAN 196      // ceil(N_NODES/256) scan blocks

// Device-verified harness dtypes: float inputs fp32, edge_index int32, output fp32.
__device__ __forceinline__ ushort f2b(float f) {
    __hip_bfloat16 b = __float2bfloat16(f);   // RNE
    return *reinterpret_cast<ushort*>(&b);
}
__device__ __forceinline__ float b2f(ushort u) {
    unsigned int x = ((unsigned int)u) << 16;
    return __uint_as_float(x);
}

typedef __bf16 bf16x8 __attribute__((ext_vector_type(8)));
typedef float  f32x4  __attribute__((ext_vector_type(4)));

#define LDA  136   // As leading dim (ushorts)
#define HPAD 36    // Hs leading dim (floats)
#define MPAD 40    // Ms leading dim (ushorts), 80B rows -> 16B-aligned

// ---------------------------------------------------------------------------
// prep: repack weights into MFMA-fragment-major bf16 buffers. (unchanged)
__global__ __launch_bounds__(256) void prep(const float* __restrict__ we2,
                                            const float* __restrict__ we1,
                                            const float* __restrict__ wroot,
                                            const float* __restrict__ wih,
                                            const float* __restrict__ whh,
                                            ushort* __restrict__ we2B,
                                            ushort* __restrict__ we1B,
                                            ushort* __restrict__ wgB) {
    int i = blockIdx.x * 256 + threadIdx.x;
    if (i < 16384) {
        int l = i & 63, f = i >> 6;           // f = bn*16 + nt*4 + kt
        int kt = f & 3, nt = (f >> 2) & 3, bn = f >> 4;
        int lr = l & 15, lg = l >> 4;
        int n = bn * 64 + nt * 16 + lr;
        int k0 = kt * 32 + lg * 8;
        ushort tmp[8];
#pragma unroll
        for (int j = 0; j < 8; ++j) tmp[j] = f2b(we2[(size_t)(k0 + j) * 1024 + n]);
        *(uint4*)(we2B + (size_t)i * 8) = *(uint4*)tmp;
    } else if (i < 16896) {
        int u = i - 16384;
        int l = u & 63, nt = u >> 6;
        int lr = l & 15, lg = l >> 4;
        int n = nt * 16 + lr;
        ushort tmp[8];
#pragma unroll
        for (int j = 0; j < 8; ++j) {
            int k = lg * 8 + j;
            tmp[j] = (k < EDGE_IN) ? f2b(we1[(size_t)k * EHID + n]) : (ushort)0;
        }
        *(uint4*)(we1B + (size_t)u * 8) = *(uint4*)tmp;
    } else if (i < 17792) {
        int u = i - 16896;
        int l = u & 63;
        int lr = l & 15, lg = l >> 4;
        ushort tmp[8];
        if (u < 128) {            // Wroot [i][o] row-major
            int nt = u >> 6;
#pragma unroll
            for (int j = 0; j < 8; ++j)
                tmp[j] = f2b(wroot[(size_t)(lg * 8 + j) * DD + nt * 16 + lr]);
        } else if (u < 512) {     // Wih [3D][D] row-major, B[n=gate-row][k=i]
            int nt = (u - 128) >> 6;
#pragma unroll
            for (int j = 0; j < 8; ++j)
                tmp[j] = f2b(wih[(size_t)(nt * 16 + lr) * DD + lg * 8 + j]);
        } else {                  // Whh
            int nt = (u - 512) >> 6;
#pragma unroll
            for (int j = 0; j < 8; ++j)
                tmp[j] = f2b(whh[(size_t)(nt * 16 + lr) * DD + lg * 8 + j]);
        }
        *(uint4*)(wgB + (size_t)u * 8) = *(uint4*)tmp;
    }
}

// ---------------------------------------------------------------------------
// CSR build (one-time): indegree hist -> multi-block exclusive scan -> fill.
// R7: msg is written at the SORTED slot, so conv_gru's gather is contiguous.
__global__ __launch_bounds__(256) void hist(const int* __restrict__ ei,
                                            int* __restrict__ cnt) {
    int e = blockIdx.x * 256 + threadIdx.x;
    if (e < N_EDGES) atomicAdd(&cnt[ei[N_EDGES + e]], 1);
}

// Per-block exclusive scan of cnt (in place), block totals -> bsum.
__global__ __launch_bounds__(256) void scan1(int* __restrict__ cnt,
                                             int* __restrict__ bsum) {
    __shared__ int wsum[4];
    int b = blockIdx.x, t = threadIdx.x;
    int lane = t & 63, wid = t >> 6;
    int i = b * 256 + t;
    int v = (i < N_NODES) ? cnt[i] : 0;
    int s = v;
#pragma unroll
    for (int off = 1; off < 64; off <<= 1) {
        int u = __shfl_up(s, off);
        if (lane >= off) s += u;
    }
    if (lane == 63) wsum[wid] = s;
    __syncthreads();
    if (t == 0) {
        int a = 0;
#pragma unroll
        for (int k = 0; k < 4; ++k) { int tmp = wsum[k]; wsum[k] = a; a += tmp; }
    }
    __syncthreads();
    int excl = s - v + wsum[wid];
    if (i < N_NODES) cnt[i] = excl;
    if (t == 255) bsum[b] = excl + v;
}

// Exclusive scan of the NSCAN block sums (single block, NSCAN <= 256).
__global__ __launch_bounds__(256) void scan2(int* __restrict__ bsum) {
    __shared__ int wsum[4];
    int t = threadIdx.x;
    int lane = t & 63, wid = t >> 6;
    int v = (t < NSCAN) ? bsum[t] : 0;
    int s = v;
#pragma unroll
    for (int off = 1; off < 64; off <<= 1) {
        int u = __shfl_up(s, off);
        if (lane >= off) s += u;
    }
    if (lane == 63) wsum[wid] = s;
    __syncthreads();
    if (t == 0) {
        int a = 0;
#pragma unroll
        for (int k = 0; k < 4; ++k) { int tmp = wsum[k]; wsum[k] = a; a += tmp; }
    }
    __syncthreads();
    if (t < NSCAN) bsum[t] = s - v + wsum[wid];
}

// off = cur = local-scan + block offset.
__global__ __launch_bounds__(256) void scan3(const int* __restrict__ cnt,
                                             const int* __restrict__ bsum,
                                             int* __restrict__ off,
                                             int* __restrict__ cur) {
    int i = blockIdx.x * 256 + threadIdx.x;
    if (i < N_NODES) {
        int o = cnt[i] + bsum[blockIdx.x];
        off[i] = o;
        cur[i] = o;
    }
}

// Emit perm (sorted-pos -> original edge) and srcs (sorted src node ids).
__global__ __launch_bounds__(256) void scatter_fill(const int* __restrict__ ei,
                                                    int* __restrict__ cur,
                                                    int* __restrict__ perm,
                                                    int* __restrict__ srcs) {
    int e = blockIdx.x * 256 + threadIdx.x;
    if (e >= N_EDGES) return;
    int d = ei[N_EDGES + e];
    int pos = atomicAdd(&cur[d], 1);
    perm[pos] = e;
    srcs[pos] = ei[e];
}

// ---------------------------------------------------------------------------
// node_init (round-10 proven form): thread = node, uniform LDS weight reads.
__global__ __launch_bounds__(256) void node_init(const float* __restrict__ x,
                                                 const float* __restrict__ Wn,
                                                 const float* __restrict__ bn,
                                                 float* __restrict__ h) {
    __shared__ float Wns[NODE_IN * DD];   // 8 KB
    __shared__ float bns[DD];
    int t = threadIdx.x;
    for (int i = t; i < NODE_IN * DD; i += 256) Wns[i] = Wn[i];
    if (t < DD) bns[t] = bn[t];
    __syncthreads();
    int n = blockIdx.x * 256 + t;
    if (n >= N_NODES) return;
    float xr[NODE_IN];
    const float4* xp = (const float4*)(x + (size_t)n * NODE_IN);
#pragma unroll
    for (int q = 0; q < NODE_IN / 4; ++q) *(float4*)&xr[q * 4] = xp[q];
    float out[DD];
#pragma unroll
    for (int o = 0; o < DD; ++o) {
        float s = bns[o];
#pragma unroll
        for (int i = 0; i < NODE_IN; ++i) s += xr[i] * Wns[i * DD + o];
        out[o] = fmaxf(s, 0.f);
    }
    float4* hp = (float4*)(h + (size_t)n * DD);
#pragma unroll
    for (int q = 0; q < DD / 4; ++q) hp[q] = *(float4*)&out[q * 4];
}

// ---------------------------------------------------------------------------
// fused_msg R7: R6 compute body unchanged. Edge identity now flows through
// perm/srcs (dst-sorted order); msg is written at the SORTED slot e, making
// conv_gru's per-node gather contiguous. R1 precedent: indirection costs
// ~+4us/dispatch, +4MB FETCH, nothing else.
__global__ __launch_bounds__(256, 4) void fused_msg(const float* __restrict__ ea,
                                                    const ushort* __restrict__ we1B,
                                                    const float* __restrict__ be1,
                                                    const ushort* __restrict__ we2B,
                                                    const float* __restrict__ be2,
                                                    const int* __restrict__ perm,
                                                    const int* __restrict__ srcs,
                                                    const float* __restrict__ h,
                                                    ushort* __restrict__ msg) {
    __shared__ __attribute__((aligned(16))) ushort AsHs[EPB * LDA];  // 34816 B
    __shared__ float b1s[EHID];                                      // 512 B
    __shared__ float be2s[DD * DD];                                  // 4096 B
    float* Hs = (float*)AsHs;            // [128][HPAD] fp32 view (phase B)
    ushort* Bs = AsHs + 9216;            // bytes [18432, 34816): bn weight tile
    ushort* Ms = AsHs;                   // [128][MPAD] bf16 m staging (tail)

    int t = threadIdx.x;
    if (t < EHID) b1s[t] = be1[t];
    for (int i = t; i < DD * DD; i += 256) be2s[i] = be2[i];

    int w = t >> 6, l = t & 63;
    int lr = l & 15, lg = l >> 4;
    int e0 = blockIdx.x * EPB;

    // Phase A input fragments from global via perm (sorted order)
    bf16x8 afe[2];
#pragma unroll
    for (int mi = 0; mi < 2; ++mi) {
        int e = e0 + (w * 2 + mi) * 16 + lr;
        ushort tmp[8] = {0, 0, 0, 0, 0, 0, 0, 0};
        if (lg < 2 && e < N_EDGES) {
            int pe = perm[e];
            const float4* p = (const float4*)(ea + (size_t)pe * EDGE_IN + lg * 8);
            float4 a = p[0], b = p[1];
            tmp[0] = f2b(a.x); tmp[1] = f2b(a.y); tmp[2] = f2b(a.z); tmp[3] = f2b(a.w);
            tmp[4] = f2b(b.x); tmp[5] = f2b(b.y); tmp[6] = f2b(b.z); tmp[7] = f2b(b.w);
        }
        afe[mi] = *(bf16x8*)tmp;
    }
    __syncthreads();   // (1) b1s ready

    // Phase A: g = relu(ea@We1+be1) via MFMA -> bf16 As[128][128]
#pragma unroll
    for (int nt = 0; nt < 8; ++nt) {
        bf16x8 bfe = *(const bf16x8*)(we1B + (size_t)((nt << 6) + l) * 8);
        int kh = nt * 16 + lr;
        float bb = b1s[kh];
#pragma unroll
        for (int mi = 0; mi < 2; ++mi) {
            f32x4 acc = (f32x4){0.f, 0.f, 0.f, 0.f};
            acc = __builtin_amdgcn_mfma_f32_16x16x32_bf16(afe[mi], bfe, acc, 0, 0, 0);
#pragma unroll
            for (int r = 0; r < 4; ++r)
                AsHs[((w * 2 + mi) * 16 + lg * 4 + r) * LDA + kh] = f2b(fmaxf(acc[r] + bb, 0.f));
        }
    }
    __syncthreads();   // (2) As complete

    bf16x8 afrag[2][4];
#pragma unroll
    for (int mi = 0; mi < 2; ++mi)
#pragma unroll
        for (int kt = 0; kt < 4; ++kt)
            afrag[mi][kt] = *(const bf16x8*)(&AsHs[((w * 2 + mi) * 16 + lr) * LDA + kt * 32 + lg * 8]);
    __syncthreads();   // (3) As reads done -> region becomes Hs + Bs

    // Gather h[srcs[e]] into Hs (2 threads per edge row; srcs is sorted-order)
    {
        int row = t >> 1, half = t & 1;
        int e = e0 + row;
        float4* hd = (float4*)(Hs + row * HPAD) + half * 4;
        if (e < N_EDGES) {
            const float4* hr = (const float4*)(h + (size_t)srcs[e] * DD) + half * 4;
#pragma unroll
            for (int q = 0; q < 4; ++q) hd[q] = hr[q];
        } else {
            float4 z = make_float4(0.f, 0.f, 0.f, 0.f);
#pragma unroll
            for (int q = 0; q < 4; ++q) hd[q] = z;
        }
    }
    // Stage bn=0 weight tile: L2 -> LDS DMA, no VGPR round-trip.
#pragma unroll
    for (int q = 0; q < 4; ++q) {
        const ushort* gsrc = we2B + (size_t)(q * 256 + t) * 8;          // per-lane
        ushort* ldst = Bs + (size_t)(q * 256 + w * 64) * 8;             // wave-uniform
        __builtin_amdgcn_global_load_lds(
            (const __attribute__((address_space(1))) unsigned int*)gsrc,
            (__attribute__((address_space(3))) unsigned int*)ldst, 16, 0, 0);
    }
    asm volatile("s_waitcnt vmcnt(0)" ::: "memory");
    __syncthreads();   // (4) Hs + Bs(0) ready

    float m_acc[2][4][2];
#pragma unroll
    for (int mi = 0; mi < 2; ++mi)
#pragma unroll
        for (int r = 0; r < 4; ++r) { m_acc[mi][r][0] = 0.f; m_acc[mi][r][1] = 0.f; }

    for (int bn = 0; bn < 16; ++bn) {
        float bv[4];
#pragma unroll
        for (int nt = 0; nt < 4; ++nt) bv[nt] = be2s[bn * 64 + nt * 16 + lr];

        f32x4 acc[2][4];
#pragma unroll
        for (int mi = 0; mi < 2; ++mi)
#pragma unroll
            for (int nt = 0; nt < 4; ++nt) acc[mi][nt] = (f32x4){0.f, 0.f, 0.f, 0.f};

#pragma unroll
        for (int kt = 0; kt < 4; ++kt) {
            const ushort* base = Bs + (size_t)(kt * 64 + l) * 8;
            bf16x8 b0 = *(const bf16x8*)(base);
            bf16x8 b1 = *(const bf16x8*)(base + 2048);
            bf16x8 b2 = *(const bf16x8*)(base + 4096);
            bf16x8 b3 = *(const bf16x8*)(base + 6144);
#pragma unroll
            for (int mi = 0; mi < 2; ++mi) {
                acc[mi][0] = __builtin_amdgcn_mfma_f32_16x16x32_bf16(afrag[mi][kt], b0, acc[mi][0], 0, 0, 0);
                acc[mi][1] = __builtin_amdgcn_mfma_f32_16x16x32_bf16(afrag[mi][kt], b1, acc[mi][1], 0, 0, 0);
                acc[mi][2] = __builtin_amdgcn_mfma_f32_16x16x32_bf16(afrag[mi][kt], b2, acc[mi][2], 0, 0, 0);
                acc[mi][3] = __builtin_amdgcn_mfma_f32_16x16x32_bf16(afrag[mi][kt], b3, acc[mi][3], 0, 0, 0);
            }
        }

        // Fold: col=bn*64+nt*16+lr -> i=2bn+(nt>>1), o=16*(nt&1)+lr
#pragma unroll
        for (int mi = 0; mi < 2; ++mi) {
#pragma unroll
            for (int r = 0; r < 4; ++r) {
                int row = (w * 2 + mi) * 16 + lg * 4 + r;
                float2 hv = *(const float2*)(Hs + row * HPAD + bn * 2);
#pragma unroll
                for (int nt = 0; nt < 4; ++nt) {
                    float hi = (nt >> 1) ? hv.y : hv.x;
                    m_acc[mi][r][nt & 1] += hi * (acc[mi][nt][r] + bv[nt]);
                }
            }
        }

        if (bn < 15) {
            __syncthreads();   // all waves done reading Bs(bn)
#pragma unroll
            for (int q = 0; q < 4; ++q) {
                const ushort* gsrc = we2B + (size_t)(bn + 1) * 8192 + (size_t)(q * 256 + t) * 8;
                ushort* ldst = Bs + (size_t)(q * 256 + w * 64) * 8;
                __builtin_amdgcn_global_load_lds(
                    (const __attribute__((address_space(1))) unsigned int*)gsrc,
                    (__attribute__((address_space(3))) unsigned int*)ldst, 16, 0, 0);
            }
            asm volatile("s_waitcnt vmcnt(0)" ::: "memory");
            __syncthreads();   // Bs(bn+1) ready
        }
    }

    // Tail: m -> LDS (bf16) -> coalesced stores at the SORTED slot e.
    __syncthreads();   // all folds done reading Hs before Ms overwrites it
#pragma unroll
    for (int mi = 0; mi < 2; ++mi) {
#pragma unroll
        for (int r = 0; r < 4; ++r) {
            int row = (w * 2 + mi) * 16 + lg * 4 + r;
            Ms[row * MPAD + lr]      = f2b(m_acc[mi][r][0]);
            Ms[row * MPAD + lr + 16] = f2b(m_acc[mi][r][1]);
        }
    }
    __syncthreads();
    {
        int row = t >> 1, half = t & 1;
        int e = e0 + row;
        if (e < N_EDGES) {
            const uint4* src = (const uint4*)(Ms + row * MPAD);
            uint4* dst = (uint4*)(msg + (size_t)e * DD);
            dst[half * 2]     = src[half * 2];
            dst[half * 2 + 1] = src[half * 2 + 1];
        }
    }
}

// ---------------------------------------------------------------------------
// conv_gru R7: msg rows for node n are CONTIGUOUS [off[n], off[n+1]) — no
// perm indirection, sequential 64B rows. h updated IN PLACE (h aliases d_out).
__global__ __launch_bounds__(256) void conv_gru(const ushort* __restrict__ msg,
                                                const int* __restrict__ off,
                                                float* __restrict__ h,
                                                const ushort* __restrict__ wgB,
                                                const float* __restrict__ bconv,
                                                const float* __restrict__ bih,
                                                const float* __restrict__ bhh) {
    __shared__ __attribute__((aligned(16))) ushort Ah[64 * 40];   // 5120 B
    __shared__ __attribute__((aligned(16))) ushort Ac[64 * 40];   // 5120 B
    __shared__ float hs[64 * 33];                                 // 8448 B
    __shared__ float bcs[DD], bis[3 * DD], bhs[3 * DD];
    int t = threadIdx.x;
    int base = blockIdx.x * 64;

    for (int idx = t; idx < 64 * DD; idx += 256) {
        int row = idx >> 5, col = idx & 31;
        int n = base + row;
        float v = (n < N_NODES) ? h[(size_t)n * DD + col] : 0.f;
        hs[row * 33 + col] = v;
        Ah[row * 40 + col] = f2b(v);
    }
    if (t < DD) bcs[t] = bconv[t];
    if (t < 3 * DD) { bis[t] = bih[t]; bhs[t] = bhh[t]; }
    __syncthreads();

    int w = t >> 6, l = t & 63;
    int lr = l & 15, lg = l >> 4;
    const f32x4 zro = (f32x4){0.f, 0.f, 0.f, 0.f};

    bf16x8 ah = *(const bf16x8*)(&Ah[(w * 16 + lr) * 40 + lg * 8]);

    // conv GEMM (2 n-tiles, K=32)
    f32x4 dcv[2];
#pragma unroll
    for (int nt = 0; nt < 2; ++nt) {
        bf16x8 b = *(const bf16x8*)(wgB + (size_t)(nt * 64 + l) * 8);
        dcv[nt] = __builtin_amdgcn_mfma_f32_16x16x32_bf16(ah, b, zro, 0, 0, 0);
    }
    // epilogue: conv = relu(dcv + contiguous-gather(msg) + bc) -> bf16 Ac
#pragma unroll
    for (int r = 0; r < 4; ++r) {
        int row = w * 16 + lg * 4 + r;
        int n = base + row;
        float a0 = 0.f, a1 = 0.f;
        if (n < N_NODES) {
            int beg = off[n];
            int end = (n + 1 < N_NODES) ? off[n + 1] : N_EDGES;
            for (int j = beg; j < end; ++j) {
                const ushort* mr = msg + (size_t)j * DD;
                a0 += b2f(mr[lr]);
                a1 += b2f(mr[lr + 16]);
            }
        }
        Ac[row * 40 + lr]      = f2b(fmaxf(dcv[0][r] + a0 + bcs[lr], 0.f));
        Ac[row * 40 + lr + 16] = f2b(fmaxf(dcv[1][r] + a1 + bcs[lr + 16], 0.f));
    }
    __syncthreads();

    bf16x8 ac = *(const bf16x8*)(&Ac[(w * 16 + lr) * 40 + lg * 8]);

    // gate GEMMs: gi = conv@Wih^T (+bi), gh = h@Whh^T (+bh); 6 n-tiles each
    f32x4 gi[6], gh[6];
#pragma unroll
    for (int nt = 0; nt < 6; ++nt) {
        bf16x8 bi_ = *(const bf16x8*)(wgB + (size_t)(128 + nt * 64 + l) * 8);
        gi[nt] = __builtin_amdgcn_mfma_f32_16x16x32_bf16(ac, bi_, zro, 0, 0, 0);
        bf16x8 bh_ = *(const bf16x8*)(wgB + (size_t)(512 + nt * 64 + l) * 8);
        gh[nt] = __builtin_amdgcn_mfma_f32_16x16x32_bf16(ah, bh_, zro, 0, 0, 0);
    }

    // elementwise GRU in D-layout: col = gate*32 + ch*16 + lr -> tile gate*2+ch
#pragma unroll
    for (int r = 0; r < 4; ++r) {
        int row = w * 16 + lg * 4 + r;
        int n = base + row;
        if (n >= N_NODES) continue;
#pragma unroll
        for (int ch = 0; ch < 2; ++ch) {
            int o = ch * 16 + lr;
            float girv = gi[ch][r]     + bis[o];
            float gizv = gi[2 + ch][r] + bis[DD + o];
            float ginv = gi[4 + ch][r] + bis[2 * DD + o];
            float ghrv = gh[ch][r]     + bhs[o];
            float ghzv = gh[2 + ch][r] + bhs[DD + o];
            float ghnv = gh[4 + ch][r] + bhs[2 * DD + o];
            float R  = 1.f / (1.f + expf(-(girv + ghrv)));
            float Z  = 1.f / (1.f + expf(-(gizv + ghzv)));
            float Nn = tanhf(ginv + R * ghnv);
            float hold = hs[row * 33 + o];
            float hnew = (1.f - Z) * Nn + Z * hold;
            h[(size_t)n * DD + o] = hnew;   // in place; h aliases d_out
        }
    }
}

// ---------------------------------------------------------------------------
extern "C" void kernel_launch(void* const* d_in, const int* in_sizes, int n_in,
                              void* d_out, int out_size, void* d_ws, size_t ws_size,
                              hipStream_t stream) {
    const float* x    = (const float*)d_in[0];
    const int*   ei   = (const int*)d_in[1];
    const float* ea   = (const float*)d_in[2];
    const float* Wn   = (const float*)d_in[3];
    const float* bn   = (const float*)d_in[4];
    const float* We1  = (const float*)d_in[5];
    const float* be1  = (const float*)d_in[6];
    const float* We2  = (const float*)d_in[7];
    const float* be2  = (const float*)d_in[8];
    const float* Wroot= (const float*)d_in[9];
    const float* bconv= (const float*)d_in[10];
    const float* Wih  = (const float*)d_in[11];
    const float* Whh  = (const float*)d_in[12];
    const float* bih  = (const float*)d_in[13];
    const float* bhh  = (const float*)d_in[14];

    // ---- Workspace: 11.69 MB (< proven 13.08 MB). h aliases d_out. ----
    char* ws = (char*)d_ws;
    ushort* msg  = (ushort*)(ws);                   // 9,600,000 E x 32 bf16 (dst-sorted)
    ushort* we2B = (ushort*)(ws + 9600000);         //   262,144 fragment-major We2T
    ushort* we1B = (ushort*)(ws + 9862144);         //     8,192 fragment-major We1T
    ushort* wgB  = (ushort*)(ws + 9870336);         //    14,336 fragment-major GRU weights
    int*    cnt  = (int*)(ws + 9884672);            //   200,000 hist / local scan
    int*    off  = (int*)(ws + 10084672);           //   200,000 CSR offsets
    int*    cur  = (int*)(ws + 10284672);           //   200,000 fill cursors
    int*    perm = (int*)(ws + 10484672);           //   600,000 sorted-pos -> orig edge
    int*    srcs = (int*)(ws + 11084672);           //   600,000 src ids, sorted order
    int*    bsum = (int*)(ws + 11684672);           //     1,024 scan block sums
    float*  h    = (float*)d_out;                   // 6.4 MB node state (= output)

    // One-time CSR build (multi-block scan)
    hipMemsetAsync(cnt, 0, (size_t)N_NODES * sizeof(int), stream);
    prep<<<70, 256, 0, stream>>>(We2, We1, Wroot, Wih, Whh, we2B, we1B, wgB);
    node_init<<<(N_NODES + 255) / 256, 256, 0, stream>>>(x, Wn, bn, h);
    hist<<<(N_EDGES + 255) / 256, 256, 0, stream>>>(ei, cnt);
    scan1<<<NSCAN, 256, 0, stream>>>(cnt, bsum);
    scan2<<<1, 256, 0, stream>>>(bsum);
    scan3<<<NSCAN, 256, 0, stream>>>(cnt, bsum, off, cur);
    scatter_fill<<<(N_EDGES + 255) / 256, 256, 0, stream>>>(ei, cur, perm, srcs);

    for (int step = 0; step < STEPS; ++step) {
        fused_msg<<<(N_EDGES + EPB - 1) / EPB, 256, 0, stream>>>(ea, we1B, be1, we2B, be2,
                                                                 perm, srcs, h, msg);
        conv_gru<<<(N_NODES + 63) / 64, 256, 0, stream>>>(msg, off, h, wgB,
                                                          bconv, bih, bhh);
    }
}